// Round 8
// baseline (165.460 us; speedup 1.0000x reference)
//
#include <hip/hip_runtime.h>

#define EPS 1e-6f
#define REC_W 16   // LDS words per half-record region (64 B per pixel per stage)

__device__ __forceinline__ float3 ld3(const float* p, int i) {
    return make_float3(p[3*i+0], p[3*i+1], p[3*i+2]);
}
__device__ __forceinline__ float3 add3(float3 a, float3 b) {
    return make_float3(a.x+b.x, a.y+b.y, a.z+b.z);
}
__device__ __forceinline__ float3 sub3(float3 a, float3 b) {
    return make_float3(a.x-b.x, a.y-b.y, a.z-b.z);
}
__device__ __forceinline__ float3 scale3(float s, float3 a) {
    return make_float3(s*a.x, s*a.y, s*a.z);
}
__device__ __forceinline__ float dot3(float3 a, float3 b) {
    return a.x*b.x + a.y*b.y + a.z*b.z;
}
__device__ __forceinline__ float3 norm3(float3 a) {
    float n = sqrtf(dot3(a, a));
    float inv = 1.0f / fmaxf(n, EPS);
    return scale3(inv, a);
}
__device__ __forceinline__ void wave_lds_fence() {
    // Intra-wave producer->consumer through LDS: compiler barrier + drain LDS ops.
    asm volatile("s_waitcnt lgkmcnt(0)" ::: "memory");
}

// record word layout: [0..2]=p0 [3..5]=p1 [6..8]=p2 [9..17]=n0,n1,n2 [18..26]=c0,c1,c2
// global fa stride: 8 float4 (128 B, line-aligned)

// ---------------- Pass 1: face-major gather, LDS-transposed coalesced stores --
#define G_REC_W 32
__global__ __launch_bounds__(256) void gather_faces_kernel(
    const float* __restrict__ verts,
    const float* __restrict__ vnorm,
    const float* __restrict__ vcol,
    const int* __restrict__ faces,
    float4* __restrict__ fa,
    int F)
{
    __shared__ float lds[4][64 * G_REC_W];

    int lane = threadIdx.x & 63;
    int wv   = threadIdx.x >> 6;
    int waveBase = blockIdx.x * 256 + wv * 64;
    int f = waveBase + lane;
    float* myl = lds[wv];

    if (f < F) {
        int v0 = faces[3*f+0];
        int v1 = faces[3*f+1];
        int v2 = faces[3*f+2];

        union { float4 q[7]; float w[28]; } u;
#define PUT3(base, src, vi) \
        u.w[base+0] = src[3*vi+0]; \
        u.w[base+1] = src[3*vi+1]; \
        u.w[base+2] = src[3*vi+2];
        PUT3(0,  verts, v0)  PUT3(3,  verts, v1)  PUT3(6,  verts, v2)
        PUT3(9,  vnorm, v0)  PUT3(12, vnorm, v1)  PUT3(15, vnorm, v2)
        PUT3(18, vcol,  v0)  PUT3(21, vcol,  v1)  PUT3(24, vcol,  v2)
#undef PUT3
        u.w[27] = 0.0f;

#pragma unroll
        for (int s = 0; s < 7; ++s) {
            *reinterpret_cast<float4*>(&myl[lane * G_REC_W + ((s + lane) & 7) * 4]) = u.q[s];
        }
    }
    wave_lds_fence();

    int seg = lane & 7;
    int sub = lane >> 3;
#pragma unroll
    for (int it = 0; it < 8; ++it) {
        int pl = it * 8 + sub;
        int gf = waveBase + pl;
        if (gf < F) {
            float4 v;
            if (seg < 7)
                v = *reinterpret_cast<const float4*>(&myl[pl * G_REC_W + ((seg + pl) & 7) * 4]);
            else
                v = make_float4(0.f, 0.f, 0.f, 0.f);
            fa[(size_t)gf * 8 + seg] = v;
        }
    }
}

// ---------------- Pass 2: two-stage wave-cooperative gather + shade ----------
// Stage h (h=0,1): 16-lane groups fetch segments h*4..h*4+3 of 16 records per
// VMEM instr into a 4 KB/wave LDS region; lanes read their half-record to regs.
__global__ __launch_bounds__(256) void phong_kernel3(
    const int* __restrict__ p2f,
    const float* __restrict__ bary,
    const float4* __restrict__ fa,
    const float* __restrict__ light_loc,
    const float* __restrict__ l_amb,
    const float* __restrict__ l_diff,
    const float* __restrict__ l_spec,
    const float* __restrict__ m_amb,
    const float* __restrict__ m_diff,
    const float* __restrict__ m_spec,
    const float* __restrict__ shin,
    const float* __restrict__ cam,
    const float* __restrict__ bg,
    float* __restrict__ out,
    int total, int hw)
{
    __shared__ float lds[4][64 * REC_W];   // 16 KB/block

    int lane = threadIdx.x & 63;
    int wv   = threadIdx.x >> 6;
    int idx  = blockIdx.x * 256 + wv * 64 + lane;
    // grid sized so idx < total (total % 256 == 0)

    int f = p2f[idx];
    float b0 = bary[3*idx+0];
    float b1 = bary[3*idx+1];
    float b2 = bary[3*idx+2];
    int g = f < 0 ? 0 : f;

    float* myl = lds[wv];
    int seg = lane & 3;    // segment within half-record
    int sub = lane >> 2;   // record-within-group-of-16

    union { float4 q[7]; float w[28]; } r;

    // ---- Stage 0: segments 0..3 (words 0..15) ----
#pragma unroll
    for (int it = 0; it < 4; ++it) {
        int p = it * 16 + sub;
        int fp = __shfl(g, p, 64);
        float4 v = fa[(size_t)fp * 8 + seg];
        *reinterpret_cast<float4*>(&myl[p * REC_W + ((seg + p) & 3) * 4]) = v;
    }
    wave_lds_fence();
#pragma unroll
    for (int j = 0; j < 4; ++j) {
        r.q[j] = *reinterpret_cast<const float4*>(&myl[lane * REC_W + ((j + lane) & 3) * 4]);
    }
    wave_lds_fence();

    // ---- Stage 1: segments 4..7 (words 16..27 used; seg 7 is pad) ----
#pragma unroll
    for (int it = 0; it < 4; ++it) {
        int p = it * 16 + sub;
        int fp = __shfl(g, p, 64);
        float4 v = fa[(size_t)fp * 8 + 4 + seg];
        *reinterpret_cast<float4*>(&myl[p * REC_W + ((seg + p) & 3) * 4]) = v;
    }
    wave_lds_fence();
#pragma unroll
    for (int j = 0; j < 3; ++j) {
        r.q[4 + j] = *reinterpret_cast<const float4*>(&myl[lane * REC_W + ((j + lane) & 3) * 4]);
    }
    const float* h = r.w;

    int n_b = (unsigned)idx / (unsigned)hw;
    float3 loc = ld3(light_loc, n_b);
    float3 cm  = ld3(cam, n_b);

    float3 p = make_float3(
        b0*h[0] + b1*h[3] + b2*h[6],
        b0*h[1] + b1*h[4] + b2*h[7],
        b0*h[2] + b1*h[5] + b2*h[8]);
    float3 nr = make_float3(
        b0*h[9]  + b1*h[12] + b2*h[15],
        b0*h[10] + b1*h[13] + b2*h[16],
        b0*h[11] + b1*h[14] + b2*h[17]);
    float3 tx = make_float3(
        b0*h[18] + b1*h[21] + b2*h[24],
        b0*h[19] + b1*h[22] + b2*h[25],
        b0*h[20] + b1*h[23] + b2*h[26]);

    float3 n  = norm3(nr);
    float3 tl = norm3(sub3(loc, p));
    float cos_angle = dot3(n, tl);
    float cos_pos = fmaxf(cos_angle, 0.0f);
    float smask = (cos_angle > 0.0f) ? 1.0f : 0.0f;
    float cos_m = cos_angle * smask;

    float3 vd = norm3(sub3(cm, p));
    float3 refl = add3(scale3(-1.0f, tl), scale3(2.0f * cos_m, n));
    float alpha = fmaxf(dot3(vd, refl), 0.0f) * smask;

    float sh = shin[0];
    float spec_pow;
    if (sh == 64.0f) {                // wave-uniform branch: 6 squarings
        float a2  = alpha * alpha;
        float a4  = a2 * a2;
        float a8  = a4 * a4;
        float a16 = a8 * a8;
        float a32 = a16 * a16;
        float a64 = a32 * a32;
        spec_pow = (alpha > 0.0f) ? a64 : 0.0f;
    } else {
        spec_pow = (alpha > 0.0f) ? powf(alpha, sh) : 0.0f;
    }

    float c0o = (m_amb[0]*l_amb[0] + m_diff[0]*l_diff[0]*cos_pos) * tx.x + m_spec[0]*l_spec[0]*spec_pow;
    float c1o = (m_amb[1]*l_amb[1] + m_diff[1]*l_diff[1]*cos_pos) * tx.y + m_spec[1]*l_spec[1]*spec_pow;
    float c2o = (m_amb[2]*l_amb[2] + m_diff[2]*l_diff[2]*cos_pos) * tx.z + m_spec[2]*l_spec[2]*spec_pow;

    float4 o = (f < 0) ? make_float4(bg[0], bg[1], bg[2], 0.0f)
                       : make_float4(c0o, c1o, c2o, 1.0f);
    reinterpret_cast<float4*>(out)[idx] = o;
}

// ---------------- Fallback single-pass --------------------------------------
__global__ __launch_bounds__(256) void phong_kernel1(
    const int* __restrict__ p2f,
    const float* __restrict__ bary,
    const float* __restrict__ verts,
    const float* __restrict__ vnorm,
    const float* __restrict__ vcol,
    const int* __restrict__ faces,
    const float* __restrict__ light_loc,
    const float* __restrict__ l_amb,
    const float* __restrict__ l_diff,
    const float* __restrict__ l_spec,
    const float* __restrict__ m_amb,
    const float* __restrict__ m_diff,
    const float* __restrict__ m_spec,
    const float* __restrict__ shin,
    const float* __restrict__ cam,
    const float* __restrict__ bg,
    float* __restrict__ out,
    int total, int hw)
{
    int idx = blockIdx.x * blockDim.x + threadIdx.x;
    if (idx >= total) return;

    int f = p2f[idx];
    float4 o;
    if (f < 0) {
        o = make_float4(bg[0], bg[1], bg[2], 0.0f);
    } else {
        float b0 = bary[3*idx+0];
        float b1 = bary[3*idx+1];
        float b2 = bary[3*idx+2];
        int v0 = faces[3*f+0];
        int v1 = faces[3*f+1];
        int v2 = faces[3*f+2];

        float3 p = add3(add3(scale3(b0, ld3(verts, v0)),
                             scale3(b1, ld3(verts, v1))),
                             scale3(b2, ld3(verts, v2)));
        float3 nr = add3(add3(scale3(b0, ld3(vnorm, v0)),
                              scale3(b1, ld3(vnorm, v1))),
                              scale3(b2, ld3(vnorm, v2)));
        float3 tx = add3(add3(scale3(b0, ld3(vcol, v0)),
                              scale3(b1, ld3(vcol, v1))),
                              scale3(b2, ld3(vcol, v2)));

        int n_b = (unsigned)idx / (unsigned)hw;
        float3 loc = ld3(light_loc, n_b);
        float3 cm  = ld3(cam, n_b);

        float3 n  = norm3(nr);
        float3 tl = norm3(sub3(loc, p));
        float cos_angle = dot3(n, tl);
        float cos_pos = fmaxf(cos_angle, 0.0f);
        float smask = (cos_angle > 0.0f) ? 1.0f : 0.0f;
        float cos_m = cos_angle * smask;

        float3 vd = norm3(sub3(cm, p));
        float3 refl = add3(scale3(-1.0f, tl), scale3(2.0f * cos_m, n));
        float alpha = fmaxf(dot3(vd, refl), 0.0f) * smask;
        float spec_pow = (alpha > 0.0f) ? powf(alpha, shin[0]) : 0.0f;

        float c0o = (m_amb[0]*l_amb[0] + m_diff[0]*l_diff[0]*cos_pos) * tx.x + m_spec[0]*l_spec[0]*spec_pow;
        float c1o = (m_amb[1]*l_amb[1] + m_diff[1]*l_diff[1]*cos_pos) * tx.y + m_spec[1]*l_spec[1]*spec_pow;
        float c2o = (m_amb[2]*l_amb[2] + m_diff[2]*l_diff[2]*cos_pos) * tx.z + m_spec[2]*l_spec[2]*spec_pow;
        o = make_float4(c0o, c1o, c2o, 1.0f);
    }
    reinterpret_cast<float4*>(out)[idx] = o;
}

extern "C" void kernel_launch(void* const* d_in, const int* in_sizes, int n_in,
                              void* d_out, int out_size, void* d_ws, size_t ws_size,
                              hipStream_t stream) {
    const int*   p2f       = (const int*)  d_in[0];
    const float* bary      = (const float*)d_in[1];
    const float* verts     = (const float*)d_in[2];
    const float* vnorm     = (const float*)d_in[3];
    const float* vcol      = (const float*)d_in[4];
    const int*   faces     = (const int*)  d_in[5];
    const float* light_loc = (const float*)d_in[6];
    const float* l_amb     = (const float*)d_in[7];
    const float* l_diff    = (const float*)d_in[8];
    const float* l_spec    = (const float*)d_in[9];
    const float* m_amb     = (const float*)d_in[10];
    const float* m_diff    = (const float*)d_in[11];
    const float* m_spec    = (const float*)d_in[12];
    const float* shin      = (const float*)d_in[13];
    const float* cam       = (const float*)d_in[14];
    const float* bg        = (const float*)d_in[15];
    float* out = (float*)d_out;

    int total   = in_sizes[0];         // N*H*W*K pixels (K=1)
    int n_batch = in_sizes[6] / 3;     // N
    int hw      = total / n_batch;     // H*W*K
    int F       = in_sizes[5] / 3;     // faces

    int block = 256;
    bool ws_ok = ws_size >= (size_t)F * 128;

    if (ws_ok && (total % 256) == 0) {
        float4* fa = (float4*)d_ws;
        int grid1 = (F + block - 1) / block;
        gather_faces_kernel<<<grid1, block, 0, stream>>>(verts, vnorm, vcol, faces, fa, F);
        int grid2 = total / 256;
        phong_kernel3<<<grid2, block, 0, stream>>>(
            p2f, bary, fa, light_loc,
            l_amb, l_diff, l_spec, m_amb, m_diff, m_spec, shin, cam, bg,
            out, total, hw);
    } else {
        int grid = (total + block - 1) / block;
        phong_kernel1<<<grid, block, 0, stream>>>(
            p2f, bary, verts, vnorm, vcol, faces, light_loc,
            l_amb, l_diff, l_spec, m_amb, m_diff, m_spec, shin, cam, bg,
            out, total, hw);
    }
}

// Round 9
// 158.438 us; speedup vs baseline: 1.0443x; 1.0443x over previous
//
#include <hip/hip_runtime.h>

#define EPS 1e-6f
#define REC_W 20   // LDS dwords per record slot (80 B): 2-way bank aliasing only

__device__ __forceinline__ float3 ld3(const float* p, int i) {
    return make_float3(p[3*i+0], p[3*i+1], p[3*i+2]);
}
__device__ __forceinline__ float3 add3(float3 a, float3 b) {
    return make_float3(a.x+b.x, a.y+b.y, a.z+b.z);
}
__device__ __forceinline__ float3 sub3(float3 a, float3 b) {
    return make_float3(a.x-b.x, a.y-b.y, a.z-b.z);
}
__device__ __forceinline__ float3 scale3(float s, float3 a) {
    return make_float3(s*a.x, s*a.y, s*a.z);
}
__device__ __forceinline__ float dot3(float3 a, float3 b) {
    return a.x*b.x + a.y*b.y + a.z*b.z;
}
__device__ __forceinline__ float3 norm3(float3 a) {
    float n = sqrtf(dot3(a, a));
    float inv = 1.0f / fmaxf(n, EPS);
    return scale3(inv, a);
}
__device__ __forceinline__ void wave_lds_fence() {
    asm volatile("s_waitcnt lgkmcnt(0)" ::: "memory");
}

// ---- 64-B packed record ----------------------------------------------------
// dwords 0..6 : 9 positions as 24-bit floats (bits [24i, 24i+24)), bits 216..218 = z-sign bits
// dwords 7..12: n0.x n0.y n1.x n1.y n2.x n2.y (fp32)
// dwords 13..15: per-vertex colors, 3x10-bit fixed [0,1023]
union PK { float4 q[4]; unsigned int w[16]; float f[16]; };

__device__ __forceinline__ void pk_put24(unsigned int* w, int i, float v) {
    unsigned int b = __float_as_uint(v);
    b = b + 0x80u;                 // round mantissa to 24-bit
    unsigned int t = b >> 8;       // 24-bit payload
    int bp = 24 * i, d = bp >> 5, sh = bp & 31;
    w[d] |= t << sh;
    if (sh > 8) w[d+1] |= t >> (32 - sh);
}
__device__ __forceinline__ float pk_get24(const unsigned int* w, int i) {
    int bp = 24 * i, d = bp >> 5, sh = bp & 31;
    unsigned int v = w[d] >> sh;
    if (sh > 8) v |= w[d+1] << (32 - sh);
    return __uint_as_float(v << 8);
}

// ---------------- Pass 1: face-major pack + LDS-transposed coalesced stores --
__global__ __launch_bounds__(256) void gather_faces_kernel(
    const float* __restrict__ verts,
    const float* __restrict__ vnorm,
    const float* __restrict__ vcol,
    const int* __restrict__ faces,
    float4* __restrict__ fa,       // F * 4 float4 (64 B records)
    int F)
{
    __shared__ float lds[4][64 * REC_W];

    int lane = threadIdx.x & 63;
    int wv   = threadIdx.x >> 6;
    int waveBase = blockIdx.x * 256 + wv * 64;
    int f = waveBase + lane;
    float* myl = lds[wv];

    if (f < F) {
        int v0 = faces[3*f+0];
        int v1 = faces[3*f+1];
        int v2 = faces[3*f+2];

        PK u;
#pragma unroll
        for (int i = 0; i < 16; ++i) u.w[i] = 0u;

        float3 p0 = ld3(verts, v0), p1 = ld3(verts, v1), p2 = ld3(verts, v2);
        pk_put24(u.w, 0, p0.x); pk_put24(u.w, 1, p0.y); pk_put24(u.w, 2, p0.z);
        pk_put24(u.w, 3, p1.x); pk_put24(u.w, 4, p1.y); pk_put24(u.w, 5, p1.z);
        pk_put24(u.w, 6, p2.x); pk_put24(u.w, 7, p2.y); pk_put24(u.w, 8, p2.z);

        float3 n0 = ld3(vnorm, v0), n1 = ld3(vnorm, v1), n2 = ld3(vnorm, v2);
        u.f[7]  = n0.x; u.f[8]  = n0.y;
        u.f[9]  = n1.x; u.f[10] = n1.y;
        u.f[11] = n2.x; u.f[12] = n2.y;
        unsigned int signs = (n0.z < 0.f ? 1u : 0u) | (n1.z < 0.f ? 2u : 0u) | (n2.z < 0.f ? 4u : 0u);
        u.w[6] |= signs << 24;

        float3 c0 = ld3(vcol, v0), c1 = ld3(vcol, v1), c2 = ld3(vcol, v2);
#define QC(c) (min((unsigned int)(__builtin_roundf((c) * 1023.0f)), 1023u))
        u.w[13] = QC(c0.x) | (QC(c0.y) << 10) | (QC(c0.z) << 20);
        u.w[14] = QC(c1.x) | (QC(c1.y) << 10) | (QC(c1.z) << 20);
        u.w[15] = QC(c2.x) | (QC(c2.y) << 10) | (QC(c2.z) << 20);
#undef QC

#pragma unroll
        for (int s = 0; s < 4; ++s)
            *reinterpret_cast<float4*>(&myl[lane * REC_W + s * 4]) = u.q[s];
    }
    wave_lds_fence();

    // coalesced store: 16-lane groups store whole 64-B records of 16 consecutive faces
    int seg = lane & 3;
    int sub = lane >> 2;
#pragma unroll
    for (int it = 0; it < 4; ++it) {
        int pl = it * 16 + sub;
        int gf = waveBase + pl;
        if (gf < F) {
            float4 v = *reinterpret_cast<const float4*>(&myl[pl * REC_W + seg * 4]);
            fa[(size_t)gf * 4 + seg] = v;
        }
    }
}

// ---------------- Pass 2: wave-cooperative gather (64-B records) + shade -----
__global__ __launch_bounds__(256) void phong_kernel3(
    const int* __restrict__ p2f,
    const float* __restrict__ bary,
    const float4* __restrict__ fa,
    const float* __restrict__ light_loc,
    const float* __restrict__ l_amb,
    const float* __restrict__ l_diff,
    const float* __restrict__ l_spec,
    const float* __restrict__ m_amb,
    const float* __restrict__ m_diff,
    const float* __restrict__ m_spec,
    const float* __restrict__ shin,
    const float* __restrict__ cam,
    const float* __restrict__ bg,
    float* __restrict__ out,
    int total, int hw)
{
    __shared__ float lds[4][64 * REC_W];   // 20 KB/block

    int lane = threadIdx.x & 63;
    int wv   = threadIdx.x >> 6;
    int idx  = blockIdx.x * 256 + wv * 64 + lane;
    // grid sized so idx < total (total % 256 == 0)

    int f = p2f[idx];
    float b0 = bary[3*idx+0];
    float b1 = bary[3*idx+1];
    float b2 = bary[3*idx+2];
    int g = f < 0 ? 0 : f;

    float* myl = lds[wv];
    int seg = lane & 3;    // 16-B segment within 64-B record
    int sub = lane >> 2;   // record-within-group-of-16

    // Phase A: cooperative gather — 16 records per instruction
#pragma unroll
    for (int it = 0; it < 4; ++it) {
        int p = it * 16 + sub;
        int fp = __shfl(g, p, 64);
        float4 v = fa[(size_t)fp * 4 + seg];
        *reinterpret_cast<float4*>(&myl[p * REC_W + seg * 4]) = v;
    }
    wave_lds_fence();

    // Phase B: each lane reads its own 64-B record (2-way aliasing: free)
    PK r;
#pragma unroll
    for (int j = 0; j < 4; ++j)
        r.q[j] = *reinterpret_cast<const float4*>(&myl[lane * REC_W + j * 4]);

    // unpack
    float p0x = pk_get24(r.w, 0), p0y = pk_get24(r.w, 1), p0z = pk_get24(r.w, 2);
    float p1x = pk_get24(r.w, 3), p1y = pk_get24(r.w, 4), p1z = pk_get24(r.w, 5);
    float p2x = pk_get24(r.w, 6), p2y = pk_get24(r.w, 7), p2z = pk_get24(r.w, 8);

    unsigned int signs = r.w[6] >> 24;
    float n0x = r.f[7],  n0y = r.f[8];
    float n1x = r.f[9],  n1y = r.f[10];
    float n2x = r.f[11], n2y = r.f[12];
    float n0z = sqrtf(fmaxf(0.f, 1.f - n0x*n0x - n0y*n0y)); n0z = (signs & 1u) ? -n0z : n0z;
    float n1z = sqrtf(fmaxf(0.f, 1.f - n1x*n1x - n1y*n1y)); n1z = (signs & 2u) ? -n1z : n1z;
    float n2z = sqrtf(fmaxf(0.f, 1.f - n2x*n2x - n2y*n2y)); n2z = (signs & 4u) ? -n2z : n2z;

    const float ci = 1.0f / 1023.0f;
    unsigned int cw0 = r.w[13], cw1 = r.w[14], cw2 = r.w[15];
    float c0x = (cw0 & 1023u) * ci, c0y = ((cw0 >> 10) & 1023u) * ci, c0z = ((cw0 >> 20) & 1023u) * ci;
    float c1x = (cw1 & 1023u) * ci, c1y = ((cw1 >> 10) & 1023u) * ci, c1z = ((cw1 >> 20) & 1023u) * ci;
    float c2x = (cw2 & 1023u) * ci, c2y = ((cw2 >> 10) & 1023u) * ci, c2z = ((cw2 >> 20) & 1023u) * ci;

    float3 p = make_float3(
        b0*p0x + b1*p1x + b2*p2x,
        b0*p0y + b1*p1y + b2*p2y,
        b0*p0z + b1*p1z + b2*p2z);
    float3 nr = make_float3(
        b0*n0x + b1*n1x + b2*n2x,
        b0*n0y + b1*n1y + b2*n2y,
        b0*n0z + b1*n1z + b2*n2z);
    float3 tx = make_float3(
        b0*c0x + b1*c1x + b2*c2x,
        b0*c0y + b1*c1y + b2*c2y,
        b0*c0z + b1*c1z + b2*c2z);

    int n_b = (unsigned)idx / (unsigned)hw;
    float3 loc = ld3(light_loc, n_b);
    float3 cm  = ld3(cam, n_b);

    float3 n  = norm3(nr);
    float3 tl = norm3(sub3(loc, p));
    float cos_angle = dot3(n, tl);
    float cos_pos = fmaxf(cos_angle, 0.0f);
    float smask = (cos_angle > 0.0f) ? 1.0f : 0.0f;
    float cos_m = cos_angle * smask;

    float3 vd = norm3(sub3(cm, p));
    float3 refl = add3(scale3(-1.0f, tl), scale3(2.0f * cos_m, n));
    float alpha = fmaxf(dot3(vd, refl), 0.0f) * smask;

    float sh = shin[0];
    float spec_pow;
    if (sh == 64.0f) {                // wave-uniform: 6 squarings
        float a2  = alpha * alpha;
        float a4  = a2 * a2;
        float a8  = a4 * a4;
        float a16 = a8 * a8;
        float a32 = a16 * a16;
        float a64 = a32 * a32;
        spec_pow = (alpha > 0.0f) ? a64 : 0.0f;
    } else {
        spec_pow = (alpha > 0.0f) ? powf(alpha, sh) : 0.0f;
    }

    float c0o = (m_amb[0]*l_amb[0] + m_diff[0]*l_diff[0]*cos_pos) * tx.x + m_spec[0]*l_spec[0]*spec_pow;
    float c1o = (m_amb[1]*l_amb[1] + m_diff[1]*l_diff[1]*cos_pos) * tx.y + m_spec[1]*l_spec[1]*spec_pow;
    float c2o = (m_amb[2]*l_amb[2] + m_diff[2]*l_diff[2]*cos_pos) * tx.z + m_spec[2]*l_spec[2]*spec_pow;

    float4 o = (f < 0) ? make_float4(bg[0], bg[1], bg[2], 0.0f)
                       : make_float4(c0o, c1o, c2o, 1.0f);
    reinterpret_cast<float4*>(out)[idx] = o;
}

// ---------------- Fallback single-pass (full fp32, direct gathers) ----------
__global__ __launch_bounds__(256) void phong_kernel1(
    const int* __restrict__ p2f,
    const float* __restrict__ bary,
    const float* __restrict__ verts,
    const float* __restrict__ vnorm,
    const float* __restrict__ vcol,
    const int* __restrict__ faces,
    const float* __restrict__ light_loc,
    const float* __restrict__ l_amb,
    const float* __restrict__ l_diff,
    const float* __restrict__ l_spec,
    const float* __restrict__ m_amb,
    const float* __restrict__ m_diff,
    const float* __restrict__ m_spec,
    const float* __restrict__ shin,
    const float* __restrict__ cam,
    const float* __restrict__ bg,
    float* __restrict__ out,
    int total, int hw)
{
    int idx = blockIdx.x * blockDim.x + threadIdx.x;
    if (idx >= total) return;

    int f = p2f[idx];
    float4 o;
    if (f < 0) {
        o = make_float4(bg[0], bg[1], bg[2], 0.0f);
    } else {
        float b0 = bary[3*idx+0];
        float b1 = bary[3*idx+1];
        float b2 = bary[3*idx+2];
        int v0 = faces[3*f+0];
        int v1 = faces[3*f+1];
        int v2 = faces[3*f+2];

        float3 p = add3(add3(scale3(b0, ld3(verts, v0)),
                             scale3(b1, ld3(verts, v1))),
                             scale3(b2, ld3(verts, v2)));
        float3 nr = add3(add3(scale3(b0, ld3(vnorm, v0)),
                              scale3(b1, ld3(vnorm, v1))),
                              scale3(b2, ld3(vnorm, v2)));
        float3 tx = add3(add3(scale3(b0, ld3(vcol, v0)),
                              scale3(b1, ld3(vcol, v1))),
                              scale3(b2, ld3(vcol, v2)));

        int n_b = (unsigned)idx / (unsigned)hw;
        float3 loc = ld3(light_loc, n_b);
        float3 cm  = ld3(cam, n_b);

        float3 n  = norm3(nr);
        float3 tl = norm3(sub3(loc, p));
        float cos_angle = dot3(n, tl);
        float cos_pos = fmaxf(cos_angle, 0.0f);
        float smask = (cos_angle > 0.0f) ? 1.0f : 0.0f;
        float cos_m = cos_angle * smask;

        float3 vd = norm3(sub3(cm, p));
        float3 refl = add3(scale3(-1.0f, tl), scale3(2.0f * cos_m, n));
        float alpha = fmaxf(dot3(vd, refl), 0.0f) * smask;
        float spec_pow = (alpha > 0.0f) ? powf(alpha, shin[0]) : 0.0f;

        float c0o = (m_amb[0]*l_amb[0] + m_diff[0]*l_diff[0]*cos_pos) * tx.x + m_spec[0]*l_spec[0]*spec_pow;
        float c1o = (m_amb[1]*l_amb[1] + m_diff[1]*l_diff[1]*cos_pos) * tx.y + m_spec[1]*l_spec[1]*spec_pow;
        float c2o = (m_amb[2]*l_amb[2] + m_diff[2]*l_diff[2]*cos_pos) * tx.z + m_spec[2]*l_spec[2]*spec_pow;
        o = make_float4(c0o, c1o, c2o, 1.0f);
    }
    reinterpret_cast<float4*>(out)[idx] = o;
}

extern "C" void kernel_launch(void* const* d_in, const int* in_sizes, int n_in,
                              void* d_out, int out_size, void* d_ws, size_t ws_size,
                              hipStream_t stream) {
    const int*   p2f       = (const int*)  d_in[0];
    const float* bary      = (const float*)d_in[1];
    const float* verts     = (const float*)d_in[2];
    const float* vnorm     = (const float*)d_in[3];
    const float* vcol      = (const float*)d_in[4];
    const int*   faces     = (const int*)  d_in[5];
    const float* light_loc = (const float*)d_in[6];
    const float* l_amb     = (const float*)d_in[7];
    const float* l_diff    = (const float*)d_in[8];
    const float* l_spec    = (const float*)d_in[9];
    const float* m_amb     = (const float*)d_in[10];
    const float* m_diff    = (const float*)d_in[11];
    const float* m_spec    = (const float*)d_in[12];
    const float* shin      = (const float*)d_in[13];
    const float* cam       = (const float*)d_in[14];
    const float* bg        = (const float*)d_in[15];
    float* out = (float*)d_out;

    int total   = in_sizes[0];         // N*H*W*K pixels (K=1)
    int n_batch = in_sizes[6] / 3;     // N
    int hw      = total / n_batch;     // H*W*K
    int F       = in_sizes[5] / 3;     // faces

    int block = 256;
    bool ws_ok = ws_size >= (size_t)F * 64;

    if (ws_ok && (total % 256) == 0) {
        float4* fa = (float4*)d_ws;
        int grid1 = (F + block - 1) / block;
        gather_faces_kernel<<<grid1, block, 0, stream>>>(verts, vnorm, vcol, faces, fa, F);
        int grid2 = total / 256;
        phong_kernel3<<<grid2, block, 0, stream>>>(
            p2f, bary, fa, light_loc,
            l_amb, l_diff, l_spec, m_amb, m_diff, m_spec, shin, cam, bg,
            out, total, hw);
    } else {
        int grid = (total + block - 1) / block;
        phong_kernel1<<<grid, block, 0, stream>>>(
            p2f, bary, verts, vnorm, vcol, faces, light_loc,
            l_amb, l_diff, l_spec, m_amb, m_diff, m_spec, shin, cam, bg,
            out, total, hw);
    }
}